// Round 1
// baseline (22.031 us; speedup 1.0000x reference)
//
#include <hip/hip_runtime.h>

// Problem constants
// B=2048, D=2048, H=16, Q=128, N=8192, V=128
// Mathematical identity: softmax rows sum to 1 => attn_rowsum == 1,
// so out[b,:] = x[b,:] + c, with c[d] = sum_{h,v} vmean[v] * Wo[d, h*V+v]
//            = sum_{k=0}^{2047} vmean[k & 127] * Wo[d, k].

#define NROWS 8192   // N
#define VDIM  128    // V
#define DDIM  2048   // D (= H*V = H*Q)
#define BDIM  2048   // B

// ---------------------------------------------------------------------------
// Kernel 1: per-block column sums of values [N, V].
// 64 blocks x 256 threads; block b handles rows [b*128, b*128+128).
// Each thread accumulates a fixed column-quad (float4 column group t%32).
// Writes partial[b*128 + col] (64 x 128 floats).
__global__ void col_partial_kernel(const float4* __restrict__ vals4,
                                   float* __restrict__ partial) {
    __shared__ float4 s[256];
    const int t = threadIdx.x;
    const int b = blockIdx.x;
    float4 acc = make_float4(0.f, 0.f, 0.f, 0.f);
    const int base = b * 4096;  // 128 rows * 32 float4/row
#pragma unroll
    for (int j = 0; j < 16; ++j) {
        float4 v = vals4[base + t + 256 * j];  // stride 256 f4 = 8 rows: col preserved
        acc.x += v.x; acc.y += v.y; acc.z += v.z; acc.w += v.w;
    }
    s[t] = acc;
    __syncthreads();
    if (t < 32) {
        float4 r = s[t];
#pragma unroll
        for (int k = 1; k < 8; ++k) {
            float4 v = s[t + 32 * k];
            r.x += v.x; r.y += v.y; r.z += v.z; r.w += v.w;
        }
        float* p = partial + b * VDIM + t * 4;
        p[0] = r.x; p[1] = r.y; p[2] = r.z; p[3] = r.w;
    }
}

// ---------------------------------------------------------------------------
// Kernel 2: reduce 64 partial rows -> vmean[128] (divide by N).
__global__ void reduce_vmean_kernel(const float* __restrict__ partial,
                                    float* __restrict__ vmean) {
    const int v = threadIdx.x;  // 128 threads
    float s = 0.f;
#pragma unroll
    for (int b = 0; b < 64; ++b) s += partial[b * VDIM + v];
    vmean[v] = s * (1.0f / (float)NROWS);
}

// ---------------------------------------------------------------------------
// Kernel 3: c[d] = sum_k vmean[k & 127] * Wo[d*2048 + k].
// 512 blocks x 256 threads; each wave (64 lanes) computes one d.
// Lane l reads float4s at row offset i*64 + l; (i*64+l) % 32 == l % 32, so
// each lane needs one fixed vmean float4.
__global__ void compute_c_kernel(const float4* __restrict__ Wo4,
                                 const float4* __restrict__ vm4,
                                 float* __restrict__ cvec) {
    const int t = threadIdx.x;
    const int lane = t & 63;
    const int wave = t >> 6;
    const int d = blockIdx.x * 4 + wave;
    const float4 vm = vm4[lane & 31];
    const float4* row = Wo4 + (size_t)d * 512;  // 2048 floats = 512 float4
    float acc = 0.f;
#pragma unroll
    for (int i = 0; i < 8; ++i) {
        float4 w = row[i * 64 + lane];
        acc += w.x * vm.x + w.y * vm.y + w.z * vm.z + w.w * vm.w;
    }
#pragma unroll
    for (int off = 32; off; off >>= 1) acc += __shfl_down(acc, off);
    if (lane == 0) cvec[d] = acc;
}

// ---------------------------------------------------------------------------
// Kernel 4: out[b, d] = x[b, d] + c[d].  Vectorized float4, grid-stride.
__global__ void add_bias_kernel(const float4* __restrict__ x4,
                                const float* __restrict__ cvec,
                                float4* __restrict__ out4) {
    const float4* __restrict__ c4 = (const float4*)cvec;
    const int n4 = (BDIM * DDIM) / 4;  // 1,048,576
    int idx = blockIdx.x * blockDim.x + threadIdx.x;
    const int stride = gridDim.x * blockDim.x;
    for (int i = idx; i < n4; i += stride) {
        float4 xv = x4[i];
        float4 cv = c4[i & 511];  // row length = 512 float4
        xv.x += cv.x; xv.y += cv.y; xv.z += cv.z; xv.w += cv.w;
        out4[i] = xv;
    }
}

// ---------------------------------------------------------------------------
extern "C" void kernel_launch(void* const* d_in, const int* in_sizes, int n_in,
                              void* d_out, int out_size, void* d_ws, size_t ws_size,
                              hipStream_t stream) {
    // inputs: 0=x [B,D], 1=keys (unused), 2=values [N,V], 3=Wq (unused), 4=Wo [D,H*V]
    const float* x      = (const float*)d_in[0];
    const float* values = (const float*)d_in[2];
    const float* Wo     = (const float*)d_in[4];
    float* out = (float*)d_out;
    float* ws  = (float*)d_ws;

    float* partial = ws;          // 64*128 = 8192 floats
    float* vmean   = ws + 8192;   // 128 floats
    float* cvec    = ws + 8320;   // 2048 floats

    col_partial_kernel<<<64, 256, 0, stream>>>((const float4*)values, partial);
    reduce_vmean_kernel<<<1, 128, 0, stream>>>(partial, vmean);
    compute_c_kernel<<<512, 256, 0, stream>>>((const float4*)Wo, (const float4*)vmean, cvec);
    add_bias_kernel<<<1024, 256, 0, stream>>>((const float4*)x, cvec, (float4*)out);
}

// Round 2
// 21.353 us; speedup vs baseline: 1.0318x; 1.0318x over previous
//
#include <hip/hip_runtime.h>

// Problem constants: B=2048, D=2048, H=16, Q=128, N=8192, V=128
// Identity: softmax rows sum to 1 => attn_rowsum == 1, so
//   out[b,:] = x[b,:] + c,   c[d] = sum_{k=0}^{2047} vmean[k & 127] * Wo[d, k]
// 3 dispatches: (1) values column partial-sums, (2) c with inline vmean
// reduction, (3) out = x + c.

#define NROWS 8192   // N
#define VDIM  128    // V
#define DDIM  2048   // D (= H*V = H*Q)
#define BDIM  2048   // B
#define P_ROWS 128   // partial-sum rows (= K1 grid size)

// ---------------------------------------------------------------------------
// Kernel 1: per-block column sums of values [N, V].
// 128 blocks x 256 threads; block b handles rows [b*64, b*64+64).
// Column-quad (t & 31) is invariant across the strided loads.
__global__ void col_partial_kernel(const float4* __restrict__ vals4,
                                   float* __restrict__ partial) {
    __shared__ float4 s[256];
    const int t = threadIdx.x;
    const int b = blockIdx.x;
    float4 acc = make_float4(0.f, 0.f, 0.f, 0.f);
    const int base = b * 2048;  // 64 rows * 32 float4/row
#pragma unroll
    for (int j = 0; j < 8; ++j) {
        float4 v = vals4[base + t + 256 * j];  // stride 256 f4 = 8 rows
        acc.x += v.x; acc.y += v.y; acc.z += v.z; acc.w += v.w;
    }
    s[t] = acc;
    __syncthreads();
    if (t < 32) {
        float4 r = s[t];
#pragma unroll
        for (int k = 1; k < 8; ++k) {
            float4 v = s[t + 32 * k];
            r.x += v.x; r.y += v.y; r.z += v.z; r.w += v.w;
        }
        float* p = partial + b * VDIM + t * 4;
        p[0] = r.x; p[1] = r.y; p[2] = r.z; p[3] = r.w;
    }
}

// ---------------------------------------------------------------------------
// Kernel 2: c[d] = sum_k vmean[k & 127] * Wo[d*2048 + k].
// 512 blocks x 256 threads. Prologue: every block redundantly reduces the
// 128x128 partial array (64 KB, L2-resident) into vmean in LDS (~0.5 us/CU).
// Then each wave computes one d: lane l reads row float4s at i*64 + l, whose
// column-quad is l & 31, so one fixed vmean quad per lane.
__global__ void compute_c_kernel(const float* __restrict__ partial,
                                 const float4* __restrict__ Wo4,
                                 float* __restrict__ cvec) {
    __shared__ float4 s[256];
    __shared__ float4 vm_lds[32];
    const int t = threadIdx.x;

    // inline vmean reduction: 128 rows x 32 quads = 4096 quads
    const float4* __restrict__ p4 = (const float4*)partial;
    float4 acc = make_float4(0.f, 0.f, 0.f, 0.f);
#pragma unroll
    for (int j = 0; j < 16; ++j) {
        float4 v = p4[t + 256 * j];  // col-quad (t & 31) invariant
        acc.x += v.x; acc.y += v.y; acc.z += v.z; acc.w += v.w;
    }
    s[t] = acc;
    __syncthreads();
    if (t < 32) {
        float4 r = s[t];
#pragma unroll
        for (int k = 1; k < 8; ++k) {
            float4 v = s[t + 32 * k];
            r.x += v.x; r.y += v.y; r.z += v.z; r.w += v.w;
        }
        const float inv = 1.0f / (float)NROWS;
        r.x *= inv; r.y *= inv; r.z *= inv; r.w *= inv;
        vm_lds[t] = r;
    }
    __syncthreads();

    const int lane = t & 63;
    const int wave = t >> 6;
    const int d = blockIdx.x * 4 + wave;
    const float4 vm = vm_lds[lane & 31];
    const float4* row = Wo4 + (size_t)d * 512;  // 2048 floats = 512 float4
    float dot = 0.f;
#pragma unroll
    for (int i = 0; i < 8; ++i) {
        float4 w = row[i * 64 + lane];
        dot += w.x * vm.x + w.y * vm.y + w.z * vm.z + w.w * vm.w;
    }
#pragma unroll
    for (int off = 32; off; off >>= 1) dot += __shfl_down(dot, off);
    if (lane == 0) cvec[d] = dot;
}

// ---------------------------------------------------------------------------
// Kernel 3: out[b, d] = x[b, d] + c[d].  Vectorized float4, grid-stride.
__global__ void add_bias_kernel(const float4* __restrict__ x4,
                                const float* __restrict__ cvec,
                                float4* __restrict__ out4) {
    const float4* __restrict__ c4 = (const float4*)cvec;
    const int n4 = (BDIM * DDIM) / 4;  // 1,048,576
    int idx = blockIdx.x * blockDim.x + threadIdx.x;
    const int stride = gridDim.x * blockDim.x;
    for (int i = idx; i < n4; i += stride) {
        float4 xv = x4[i];
        float4 cv = c4[i & 511];  // row length = 512 float4
        xv.x += cv.x; xv.y += cv.y; xv.z += cv.z; xv.w += cv.w;
        out4[i] = xv;
    }
}

// ---------------------------------------------------------------------------
extern "C" void kernel_launch(void* const* d_in, const int* in_sizes, int n_in,
                              void* d_out, int out_size, void* d_ws, size_t ws_size,
                              hipStream_t stream) {
    // inputs: 0=x [B,D], 1=keys (unused), 2=values [N,V], 3=Wq (unused), 4=Wo [D,H*V]
    const float* x      = (const float*)d_in[0];
    const float* values = (const float*)d_in[2];
    const float* Wo     = (const float*)d_in[4];
    float* out = (float*)d_out;
    float* ws  = (float*)d_ws;

    float* partial = ws;                       // 128*128 = 16384 floats
    float* cvec    = ws + P_ROWS * VDIM;       // 2048 floats

    col_partial_kernel<<<P_ROWS, 256, 0, stream>>>((const float4*)values, partial);
    compute_c_kernel<<<512, 256, 0, stream>>>(partial, (const float4*)Wo, cvec);
    add_bias_kernel<<<1024, 256, 0, stream>>>((const float4*)x, cvec, (float4*)out);
}